// Round 9
// baseline (303.281 us; speedup 1.0000x reference)
//
#include <hip/hip_runtime.h>

#define DEVI __device__ __forceinline__

typedef __attribute__((ext_vector_type(4))) float f32x4;
typedef __attribute__((ext_vector_type(8))) _Float16 f16x8;
typedef __attribute__((ext_vector_type(2))) _Float16 f16x2;
typedef __attribute__((ext_vector_type(4))) unsigned u32x4;

#if __has_builtin(__builtin_amdgcn_exp2f)
#define EXP2F __builtin_amdgcn_exp2f
#else
#define EXP2F exp2f
#endif

DEVI ushort f2h(float f) {  // RNE scalar convert (v_cvt_f16_f32)
  _Float16 h = (_Float16)f;
  return __builtin_bit_cast(ushort, h);
}

DEVI unsigned pkrtz(float a, float b) {  // v_cvt_pkrtz_f16_f32
  return __builtin_bit_cast(unsigned, __builtin_amdgcn_cvt_pkrtz(a, b));
}

DEVI void gload_lds16(const void* g, void* l) {
  typedef const unsigned int GlobU __attribute__((address_space(1)));
  typedef unsigned int LdsU __attribute__((address_space(3)));
  __builtin_amdgcn_global_load_lds((GlobU*)g, (LdsU*)l, 16, 0, 0);
}

// ---------------- fused prep: fp32->fp16 cast of x/ctx + transpose-cast of weights ----------------
// blocks 0..16383: cast (x then ctx). blocks 16384..17407: weight transpose.
__global__ __launch_bounds__(256) void prep_kernel(
    const float4* __restrict__ x, const float4* __restrict__ ctx,
    ushort4* __restrict__ xo, ushort4* __restrict__ co,
    const float* __restrict__ Wq, const float* __restrict__ Wkv,
    const float* __restrict__ Wo, ushort* __restrict__ WqT,
    ushort* __restrict__ WkvT, ushort* __restrict__ WoT) {
  __shared__ ushort tile[64][65];
  const int bid = blockIdx.x;
  const int t = threadIdx.x;
  if (bid < 16384) {
    int i = bid * 256 + t;
    const float4* src;
    ushort4* dst;
    int j;
    if (i < 2097152) { src = x; dst = xo; j = i; }
    else             { src = ctx; dst = co; j = i - 2097152; }
    float4 v = src[j];
    ushort4 o;
    o.x = f2h(v.x); o.y = f2h(v.y); o.z = f2h(v.z); o.w = f2h(v.w);
    dst[j] = o;
    return;
  }
  int bx2 = bid - 16384;        // 0..1023
  int bx = bx2 & 63;            // matrix + col-block
  int rb = (bx2 >> 6) * 64;     // row-block (16 of them)
  const float* in; ushort* out; int C, cb;
  if (bx < 16)      { in = Wq;  out = WqT;  C = 1024; cb = bx * 64; }
  else if (bx < 48) { in = Wkv; out = WkvT; C = 2048; cb = (bx - 16) * 64; }
  else              { in = Wo;  out = WoT;  C = 1024; cb = (bx - 48) * 64; }
  const int R = 1024;
  int c4 = (t & 15) * 4, r0 = t >> 4;
#pragma unroll
  for (int i = 0; i < 4; i++) {
    int r = r0 + i * 16;
    float4 v = *(const float4*)(in + (size_t)(rb + r) * C + cb + c4);
    tile[r][c4 + 0] = f2h(v.x);
    tile[r][c4 + 1] = f2h(v.y);
    tile[r][c4 + 2] = f2h(v.z);
    tile[r][c4 + 3] = f2h(v.w);
  }
  __syncthreads();
#pragma unroll
  for (int i = 0; i < 4; i++) {
    int rr = r0 + i * 16;
    ushort4 o;
    o.x = tile[c4 + 0][rr]; o.y = tile[c4 + 1][rr];
    o.z = tile[c4 + 2][rr]; o.w = tile[c4 + 3][rr];
    *(ushort4*)(out + (size_t)(cb + rr) * R + rb + c4) = o;
  }
}

// ---------------- tri-buffer fp16 GEMM core (1 barrier/iter) ----------------
// As/Bs are 3x (128x32) fp16 buffers (8KB each). Pipeline: prologue loads
// tiles 0,1 into bufs 0,1; per iter: vmcnt(4) waits own tile's 4 loads (next
// tile's 4 stay in flight), ONE s_barrier, frags+MFMA, then refill
// buf[(cur+2)%3] with tile cur+2. Safe: a wave cannot reach barrier i+1 until
// its iter-i LDS reads completed (lgkmcnt-drained before its MFMAs), and any
// overwrite of buf[i%3] (= tile i+3 stage) is issued only after barrier i+1.
// Same transformation verified on attn (R6, passed absmax).
DEVI void gemm_stage(const ushort* __restrict__ A, const ushort* __restrict__ Bt,
                     int K, int rowbase, int colbase, int tid, int wave,
                     ushort* AsC, ushort* BsC, int kk) {
#pragma unroll
  for (int i = 0; i < 2; i++) {
    int f = i * 256 + tid;
    int r = f >> 2;
    int c = (f & 3) ^ (r & 3);
    gload_lds16(A + (size_t)(rowbase + r) * K + (kk + c * 8),
                (char*)AsC + (size_t)(i * 256 + wave * 64) * 16);
    gload_lds16(Bt + (size_t)(colbase + r) * K + (kk + c * 8),
                (char*)BsC + (size_t)(i * 256 + wave * 64) * 16);
  }
}

DEVI void gemm_core(const ushort* __restrict__ A, const ushort* __restrict__ Bt,
                    const int K, int rowbase, int colbase, int tid,
                    ushort* As, ushort* Bs, f32x4 acc[4][4]) {
  const int lane = tid & 63, wave = tid >> 6;
  const int quad = lane >> 4, ln = lane & 15;
  const int wrow = (wave >> 1) * 64, wcol = (wave & 1) * 64;

  gemm_stage(A, Bt, K, rowbase, colbase, tid, wave, As, Bs, 0);
  gemm_stage(A, Bt, K, rowbase, colbase, tid, wave, As + 4096, Bs + 4096, 32);

  int cur = 0;
  for (int k0 = 0; k0 < K; k0 += 32) {
    ushort* AsC = As + cur * 4096;
    ushort* BsC = Bs + cur * 4096;

    if (k0 + 32 < K) asm volatile("s_waitcnt vmcnt(4)" ::: "memory");
    else             asm volatile("s_waitcnt vmcnt(0)" ::: "memory");
    asm volatile("s_barrier" ::: "memory");

    f16x8 a[4], b[4];
#pragma unroll
    for (int mt = 0; mt < 4; mt++) {
      int r = wrow + mt * 16 + ln;
      a[mt] = *(const f16x8*)(AsC + ((size_t)r * 4 + (quad ^ (r & 3))) * 8);
    }
#pragma unroll
    for (int nt = 0; nt < 4; nt++) {
      int r = wcol + nt * 16 + ln;
      b[nt] = *(const f16x8*)(BsC + ((size_t)r * 4 + (quad ^ (r & 3))) * 8);
    }
    __builtin_amdgcn_s_setprio(1);
#pragma unroll
    for (int mt = 0; mt < 4; mt++)
#pragma unroll
      for (int nt = 0; nt < 4; nt++)
        acc[mt][nt] = __builtin_amdgcn_mfma_f32_16x16x32_f16(a[mt], b[nt], acc[mt][nt], 0, 0, 0);
    __builtin_amdgcn_s_setprio(0);

    if (k0 + 64 < K) {
      int nxt = cur - 1; if (nxt < 0) nxt = 2;  // (cur+2)%3
      gemm_stage(A, Bt, K, rowbase, colbase, tid, wave, As + nxt * 4096, Bs + nxt * 4096, k0 + 64);
    }
    cur = cur + 1; if (cur == 3) cur = 0;
  }
}

// ---------------- fused Q + KV projection GEMM ----------------
__global__ __launch_bounds__(256, 3) void qkv_gemm(
    const ushort* __restrict__ xb, const ushort* __restrict__ cb,
    const ushort* __restrict__ WqT, const ushort* __restrict__ WkvT,
    ushort* __restrict__ Qo, ushort* __restrict__ Ko, ushort* __restrict__ Vo) {
  __shared__ ushort As[3 * 128 * 32];
  __shared__ ushort Bs[3 * 128 * 32];
  const int tid = threadIdx.x;
  const int lane = tid & 63, wave = tid >> 6;
  const int quad = lane >> 4, ln = lane & 15;
  const int cy = blockIdx.y;
  const bool isQ = cy < 8;
  const int colbase = (isQ ? cy : cy - 8) * 128;
  const int rowbase = blockIdx.x * 128;
  const int wrow = (wave >> 1) * 64, wcol = (wave & 1) * 64;
  f32x4 acc[4][4] = {};
  gemm_core(isQ ? xb : cb, isQ ? WqT : WkvT, 1024, rowbase, colbase, tid, As, Bs, acc);

  if (isQ) {
    const float qs = 0.18033688011112042f;  // 1/8 * log2(e)
#pragma unroll
    for (int nt = 0; nt < 4; nt++) {
      int col = colbase + wcol + nt * 16 + ln;
      int h = col >> 6, d = col & 63;
#pragma unroll
      for (int mt = 0; mt < 4; mt++) {
        int row = rowbase + wrow + mt * 16 + quad * 4;
        int bb = row >> 11, n = row & 2047;
        uint2 pv;
        pv.x = pkrtz(acc[mt][nt][0] * qs, acc[mt][nt][1] * qs);
        pv.y = pkrtz(acc[mt][nt][2] * qs, acc[mt][nt][3] * qs);
        *(uint2*)(Qo + (((size_t)bb * 16 + h) * 64 + d) * 2048 + n) = pv;
      }
    }
  } else {
    bool isK = (colbase < 1024);
#pragma unroll
    for (int nt = 0; nt < 4; nt++) {
      int col = colbase + wcol + nt * 16 + ln;
#pragma unroll
      for (int mt = 0; mt < 4; mt++) {
        int row = rowbase + wrow + mt * 16 + quad * 4;
        int bb = row >> 11, m = row & 2047;
        if (isK) {
          int h = col >> 6, d = col & 63;
#pragma unroll
          for (int r = 0; r < 4; r++)
            Ko[(((size_t)bb * 16 + h) * 2048 + (m + r)) * 64 + d] = f2h(acc[mt][nt][r]);
        } else {
          int c2 = col - 1024;
          int h = c2 >> 6, d = c2 & 63;
          uint2 pv;
          pv.x = pkrtz(acc[mt][nt][0], acc[mt][nt][1]);
          pv.y = pkrtz(acc[mt][nt][2], acc[mt][nt][3]);
          *(uint2*)(Vo + (((size_t)bb * 16 + h) * 64 + d) * 2048 + m) = pv;
        }
      }
    }
  }
}

// ---------------- out projection: fp32 [M][N] = A @ WoT^T + bias ----------------
__global__ __launch_bounds__(256, 3) void out_gemm(
    const ushort* __restrict__ A, const ushort* __restrict__ Bt,
    float* __restrict__ C, const float* __restrict__ bias) {
  __shared__ ushort As[3 * 128 * 32];
  __shared__ ushort Bs[3 * 128 * 32];
  const int tid = threadIdx.x;
  const int lane = tid & 63, wave = tid >> 6;
  const int quad = lane >> 4, ln = lane & 15;
  const int colbase = blockIdx.y * 128, rowbase = blockIdx.x * 128;
  const int wrow = (wave >> 1) * 64, wcol = (wave & 1) * 64;
  f32x4 acc[4][4] = {};
  gemm_core(A, Bt, 1024, rowbase, colbase, tid, As, Bs, acc);
#pragma unroll
  for (int nt = 0; nt < 4; nt++) {
    int col = colbase + wcol + nt * 16 + ln;
    float bv = bias[col];
#pragma unroll
    for (int mt = 0; mt < 4; mt++) {
      int row = rowbase + wrow + mt * 16 + quad * 4;
#pragma unroll
      for (int r = 0; r < 4; r++)
        C[(size_t)(row + r) * 1024 + col] = acc[mt][nt][r] + bv;
    }
  }
}

// ---------------- flash attention: 4 waves, 64 q/wave, tri-buffer 1-barrier ----------------
// (R6 verified kernel, 79.0us.) See R6 comments: K/V tri-buffer -> 1 barrier/
// iter; row-sum via ones-A MFMA; setprio around MFMA clusters; K rows PERMUTED
// at staging so PV B-frags assemble in registers (P never touches LDS).
__global__ __launch_bounds__(256, 2) void attn_kernel(
    const ushort* __restrict__ QT, const ushort* __restrict__ K,
    const ushort* __restrict__ VT, const float* __restrict__ xmask,
    const float* __restrict__ cmask, ushort* __restrict__ O) {
  __shared__ ushort Ks[3][64 * 64];  // 24KB tri-buffer
  __shared__ ushort Vs[3][64 * 64];  // 24KB tri-buffer
  __shared__ float CMB[2048];        // (cmask-1)*3e4 bias, whole context row
  const int tid = threadIdx.x, lane = tid & 63, wave = tid >> 6;  // wave 0..3
  const int quad = lane >> 4, ln = lane & 15;
  const int bid = blockIdx.x;
  const int qb = bid >> 6, bh6 = bid & 63, h = bh6 & 15, b = bh6 >> 4;
  const size_t bh = (size_t)b * 16 + h;
  const ushort* QTbh = QT + bh * (64 * 2048);
  const ushort* Kbh = K + bh * (2048 * 64);
  const ushort* Vbh = VT + bh * (64 * 2048);
  const int q0 = qb * 256 + wave * 64;

  // one-time: stage mask bias into LDS (0 valid / -3e4 masked), 8 floats/thread
#pragma unroll
  for (int i = 0; i < 2; i++) {
    float4 c0 = *(const float4*)(cmask + b * 2048 + tid * 8 + i * 4);
    float4 b0;
    b0.x = fmaf(c0.x, 3.0e4f, -3.0e4f); b0.y = fmaf(c0.y, 3.0e4f, -3.0e4f);
    b0.z = fmaf(c0.z, 3.0e4f, -3.0e4f); b0.w = fmaf(c0.w, 3.0e4f, -3.0e4f);
    *(float4*)(CMB + tid * 8 + i * 4) = b0;
  }

  // Q fragments from Q^T (one-time scalar loads; B-operand: n=q=ln, k=d=quad*8+j+32*kc)
  f16x8 qf[4][2];
#pragma unroll
  for (int qt = 0; qt < 4; qt++)
#pragma unroll
    for (int kc = 0; kc < 2; kc++) {
      int q = q0 + qt * 16 + ln;
#pragma unroll
      for (int j = 0; j < 8; j++)
        qf[qt][kc][j] = __builtin_bit_cast(_Float16,
            (unsigned short)QTbh[(size_t)(kc * 32 + quad * 8 + j) * 2048 + q]);
    }

  float xm[4];
#pragma unroll
  for (int qt = 0; qt < 4; qt++) xm[qt] = xmask[b * 2048 + q0 + qt * 16 + ln];

  __syncthreads();  // CMB staged; drains all scalar VMEM (vmcnt clean for pipeline)

  // staging: 2 K-gloads + 2 V-gloads per tile per thread
  auto STAGE = [&](int t, int buf) {
#pragma unroll
    for (int i = 0; i < 2; i++) {
      int f = i * 256 + tid;
      int r = f >> 3;
      int c = (f & 7) ^ (r & 7);
      int rp = (r & 32) | ((r & 12) << 1) | ((r & 16) >> 2) | (r & 3);
      gload_lds16(Kbh + (size_t)(t * 64 + rp) * 64 + c * 8, (char*)Ks[buf] + (size_t)f * 16);
      gload_lds16(Vbh + (size_t)r * 2048 + (t * 64 + c * 8), (char*)Vs[buf] + (size_t)f * 16);
    }
  };

  // prologue: prefetch tiles 0 and 1 into bufs 0 and 1
  STAGE(0, 0);
  STAGE(1, 1);

  // ones A-fragment for the row-sum MFMA (D[r][q] = sum_k P[k][q] for all r)
  f16x8 onesf;
#pragma unroll
  for (int j = 0; j < 8; j++) onesf[j] = (_Float16)1.0f;

  f32x4 o[4][4] = {};    // o[dt][qt]: rows d = dt*16+quad*4+r, col q = ln
  f32x4 lsum[4] = {};    // per-qt row-sum accumulators (all regs equal)

  int cur = 0;
  for (int kb = 0; kb < 32; kb++) {
    const int m0 = kb * 64;
    const ushort* KsC = Ks[cur];
    const ushort* VsC = Vs[cur];

    if (kb < 31) asm volatile("s_waitcnt vmcnt(4)" ::: "memory");
    else         asm volatile("s_waitcnt vmcnt(0)" ::: "memory");
    asm volatile("s_barrier" ::: "memory");

    // mask bias from LDS (broadcast reads), at PERMUTED key positions:
    // tile kt rows quad*4+{0..3} hold keys (kt>>1)*32 + quad*8 + (kt&1)*4 + {0..3}
    f32x4 bias4[4];
#pragma unroll
    for (int kt = 0; kt < 4; kt++)
      bias4[kt] = *(const f32x4*)(CMB + m0 + (kt >> 1) * 32 + quad * 8 + (kt & 1) * 4);

    // S^T: s[kt][qt], C-init = mask bias (permuted key order)
    f32x4 s[4][4];
#pragma unroll
    for (int kt = 0; kt < 4; kt++)
#pragma unroll
      for (int qt = 0; qt < 4; qt++) s[kt][qt] = bias4[kt];
    __builtin_amdgcn_s_setprio(1);
#pragma unroll
    for (int kc = 0; kc < 2; kc++) {
#pragma unroll
      for (int kt = 0; kt < 4; kt++) {
        int r = kt * 16 + ln;
        f16x8 ka = *(const f16x8*)(KsC + ((size_t)r * 8 + ((kc * 4 + quad) ^ (r & 7))) * 8);
#pragma unroll
        for (int qt = 0; qt < 4; qt++)
          s[kt][qt] = __builtin_amdgcn_mfma_f32_16x16x32_f16(ka, qf[qt][kc], s[kt][qt], 0, 0, 0);
      }
    }
    __builtin_amdgcn_s_setprio(0);

    // per 32-key half: exp2 -> pack -> PV B-frag entirely in registers;
    // row-sum folded into an extra ones-A MFMA per (kc,qt).
#pragma unroll
    for (int kc = 0; kc < 2; kc++) {
      f16x8 pf[4];
#pragma unroll
      for (int qt = 0; qt < 4; qt++) {
        f32x4 sA = s[kc * 2 + 0][qt];
        f32x4 sB = s[kc * 2 + 1][qt];
        u32x4 u;
        u[0] = pkrtz(EXP2F(sA[0]), EXP2F(sA[1]));
        u[1] = pkrtz(EXP2F(sA[2]), EXP2F(sA[3]));
        u[2] = pkrtz(EXP2F(sB[0]), EXP2F(sB[1]));
        u[3] = pkrtz(EXP2F(sB[2]), EXP2F(sB[3]));
        pf[qt] = __builtin_bit_cast(f16x8, u);
      }
      __builtin_amdgcn_s_setprio(1);
#pragma unroll
      for (int qt = 0; qt < 4; qt++)
        lsum[qt] = __builtin_amdgcn_mfma_f32_16x16x32_f16(onesf, pf[qt], lsum[qt], 0, 0, 0);
#pragma unroll
      for (int dt = 0; dt < 4; dt++) {
        int r = dt * 16 + ln;
        f16x8 va = *(const f16x8*)(VsC + ((size_t)r * 8 + ((kc * 4 + quad) ^ (r & 7))) * 8);
#pragma unroll
        for (int qt = 0; qt < 4; qt++)
          o[dt][qt] = __builtin_amdgcn_mfma_f32_16x16x32_f16(va, pf[qt], o[dt][qt], 0, 0, 0);
      }
      __builtin_amdgcn_s_setprio(0);
    }

    // refill buf[(cur+2)%3] with tile kb+2 (no barrier needed before this)
    if (kb < 30) {
      int nxt = cur - 1; if (nxt < 0) nxt = 2;  // (cur+2)%3
      STAGE(kb + 2, nxt);
    }
    cur = cur + 1; if (cur == 3) cur = 0;
  }

  // normalize + store O [b][n][h*64+d]; l comes straight from lsum (no shfl)
#pragma unroll
  for (int qt = 0; qt < 4; qt++) {
    float l = lsum[qt][0];
    float inv = (xm[qt] != 0.f && l > 0.f) ? (1.f / l) : 0.f;
    int n = q0 + qt * 16 + ln;
    ushort* ob = O + ((size_t)(b * 2048 + n) * 16 + h) * 64;
#pragma unroll
    for (int dt = 0; dt < 4; dt++) {
      uint2 pv;
      pv.x = pkrtz(o[dt][qt][0] * inv, o[dt][qt][1] * inv);
      pv.y = pkrtz(o[dt][qt][2] * inv, o[dt][qt][3] * inv);
      *(uint2*)(ob + dt * 16 + quad * 4) = pv;
    }
  }
}

// ---------------- host launcher ----------------
extern "C" void kernel_launch(void* const* d_in, const int* in_sizes, int n_in,
                              void* d_out, int out_size, void* d_ws, size_t ws_size,
                              hipStream_t stream) {
  const float* x   = (const float*)d_in[0];
  const float* ctx = (const float*)d_in[1];
  const float* xm  = (const float*)d_in[2];
  const float* cm  = (const float*)d_in[3];
  const float* Wq  = (const float*)d_in[4];
  const float* Wkv = (const float*)d_in[5];
  const float* Wo  = (const float*)d_in[6];
  const float* bo  = (const float*)d_in[7];

  char* ws = (char*)d_ws;
  const size_t MB = 1024 * 1024;
  ushort* xb   = (ushort*)(ws + 0);         // 16MB (x fp16; reused as O after QKV GEMM)
  ushort* cb   = (ushort*)(ws + 16 * MB);   // 16MB (context fp16)
  ushort* WqT  = (ushort*)(ws + 32 * MB);   // 2MB
  ushort* WkvT = (ushort*)(ws + 34 * MB);   // 4MB
  ushort* WoT  = (ushort*)(ws + 38 * MB);   // 2MB
  ushort* QTb  = (ushort*)(ws + 40 * MB);   // 16MB (Q transposed [b][h][d][n])
  ushort* Kb   = (ushort*)(ws + 56 * MB);   // 16MB
  ushort* VTb  = (ushort*)(ws + 72 * MB);   // 16MB
  ushort* Ob   = xb;                        // alias: x fp16 dead after QKV GEMM

  prep_kernel<<<17408, 256, 0, stream>>>((const float4*)x, (const float4*)ctx,
                                         (ushort4*)xb, (ushort4*)cb,
                                         Wq, Wkv, Wo, WqT, WkvT, WoT);
  qkv_gemm<<<dim3(64, 24), 256, 0, stream>>>(xb, cb, WqT, WkvT, QTb, Kb, VTb);
  attn_kernel<<<512, 256, 0, stream>>>(QTb, Kb, VTb, xm, cm, Ob);
  out_gemm<<<dim3(64, 8), 256, 0, stream>>>(Ob, WoT, (float*)d_out, bo);
}

// Round 10
// 293.165 us; speedup vs baseline: 1.0345x; 1.0345x over previous
//
#include <hip/hip_runtime.h>

#define DEVI __device__ __forceinline__

typedef __attribute__((ext_vector_type(4))) float f32x4;
typedef __attribute__((ext_vector_type(8))) _Float16 f16x8;
typedef __attribute__((ext_vector_type(2))) _Float16 f16x2;
typedef __attribute__((ext_vector_type(4))) unsigned u32x4;

#if __has_builtin(__builtin_amdgcn_exp2f)
#define EXP2F __builtin_amdgcn_exp2f
#else
#define EXP2F exp2f
#endif

DEVI ushort f2h(float f) {  // RNE scalar convert (v_cvt_f16_f32)
  _Float16 h = (_Float16)f;
  return __builtin_bit_cast(ushort, h);
}

DEVI unsigned pkrtz(float a, float b) {  // v_cvt_pkrtz_f16_f32
  return __builtin_bit_cast(unsigned, __builtin_amdgcn_cvt_pkrtz(a, b));
}

DEVI void gload_lds16(const void* g, void* l) {
  typedef const unsigned int GlobU __attribute__((address_space(1)));
  typedef unsigned int LdsU __attribute__((address_space(3)));
  __builtin_amdgcn_global_load_lds((GlobU*)g, (LdsU*)l, 16, 0, 0);
}

// ---------------- fused prep: fp32->fp16 cast of x/ctx + transpose-cast of weights ----------------
// blocks 0..16383: cast (x then ctx). blocks 16384..17407: weight transpose.
__global__ __launch_bounds__(256) void prep_kernel(
    const float4* __restrict__ x, const float4* __restrict__ ctx,
    ushort4* __restrict__ xo, ushort4* __restrict__ co,
    const float* __restrict__ Wq, const float* __restrict__ Wkv,
    const float* __restrict__ Wo, ushort* __restrict__ WqT,
    ushort* __restrict__ WkvT, ushort* __restrict__ WoT) {
  __shared__ ushort tile[64][65];
  const int bid = blockIdx.x;
  const int t = threadIdx.x;
  if (bid < 16384) {
    int i = bid * 256 + t;
    const float4* src;
    ushort4* dst;
    int j;
    if (i < 2097152) { src = x; dst = xo; j = i; }
    else             { src = ctx; dst = co; j = i - 2097152; }
    float4 v = src[j];
    ushort4 o;
    o.x = f2h(v.x); o.y = f2h(v.y); o.z = f2h(v.z); o.w = f2h(v.w);
    dst[j] = o;
    return;
  }
  int bx2 = bid - 16384;        // 0..1023
  int bx = bx2 & 63;            // matrix + col-block
  int rb = (bx2 >> 6) * 64;     // row-block (16 of them)
  const float* in; ushort* out; int C, cb;
  if (bx < 16)      { in = Wq;  out = WqT;  C = 1024; cb = bx * 64; }
  else if (bx < 48) { in = Wkv; out = WkvT; C = 2048; cb = (bx - 16) * 64; }
  else              { in = Wo;  out = WoT;  C = 1024; cb = (bx - 48) * 64; }
  const int R = 1024;
  int c4 = (t & 15) * 4, r0 = t >> 4;
#pragma unroll
  for (int i = 0; i < 4; i++) {
    int r = r0 + i * 16;
    float4 v = *(const float4*)(in + (size_t)(rb + r) * C + cb + c4);
    tile[r][c4 + 0] = f2h(v.x);
    tile[r][c4 + 1] = f2h(v.y);
    tile[r][c4 + 2] = f2h(v.z);
    tile[r][c4 + 3] = f2h(v.w);
  }
  __syncthreads();
#pragma unroll
  for (int i = 0; i < 4; i++) {
    int rr = r0 + i * 16;
    ushort4 o;
    o.x = tile[c4 + 0][rr]; o.y = tile[c4 + 1][rr];
    o.z = tile[c4 + 2][rr]; o.w = tile[c4 + 3][rr];
    *(ushort4*)(out + (size_t)(cb + rr) * R + rb + c4) = o;
  }
}

// ---------------- tri-buffer fp16 GEMM core (1 barrier/iter, EARLY refill) ----------------
// Refill of buf[(cur+2)%3] is issued IMMEDIATELY after the barrier (before
// frag reads/MFMA) so its loads get the whole compute body (~1500cy) to land
// before next iter's vmcnt(4), instead of ~100cy when issued at iter end.
// Safety unchanged: buf[(cur+2)%3] holds tile cur-1, last read in iter cur-1;
// every wave released from barrier cur has finished iter cur-1's reads.
DEVI void gemm_stage(const ushort* __restrict__ A, const ushort* __restrict__ Bt,
                     int K, int rowbase, int colbase, int tid, int wave,
                     ushort* AsC, ushort* BsC, int kk) {
#pragma unroll
  for (int i = 0; i < 2; i++) {
    int f = i * 256 + tid;
    int r = f >> 2;
    int c = (f & 3) ^ (r & 3);
    gload_lds16(A + (size_t)(rowbase + r) * K + (kk + c * 8),
                (char*)AsC + (size_t)(i * 256 + wave * 64) * 16);
    gload_lds16(Bt + (size_t)(colbase + r) * K + (kk + c * 8),
                (char*)BsC + (size_t)(i * 256 + wave * 64) * 16);
  }
}

DEVI void gemm_core(const ushort* __restrict__ A, const ushort* __restrict__ Bt,
                    const int K, int rowbase, int colbase, int tid,
                    ushort* As, ushort* Bs, f32x4 acc[4][4]) {
  const int lane = tid & 63, wave = tid >> 6;
  const int quad = lane >> 4, ln = lane & 15;
  const int wrow = (wave >> 1) * 64, wcol = (wave & 1) * 64;

  gemm_stage(A, Bt, K, rowbase, colbase, tid, wave, As, Bs, 0);
  gemm_stage(A, Bt, K, rowbase, colbase, tid, wave, As + 4096, Bs + 4096, 32);

  int cur = 0;
  for (int k0 = 0; k0 < K; k0 += 32) {
    ushort* AsC = As + cur * 4096;
    ushort* BsC = Bs + cur * 4096;

    if (k0 + 32 < K) asm volatile("s_waitcnt vmcnt(4)" ::: "memory");
    else             asm volatile("s_waitcnt vmcnt(0)" ::: "memory");
    asm volatile("s_barrier" ::: "memory");

    // EARLY refill: issue tile k0+64's loads now, consume LDS of tile k0 below
    if (k0 + 64 < K) {
      int nxt = cur - 1; if (nxt < 0) nxt = 2;  // (cur+2)%3
      gemm_stage(A, Bt, K, rowbase, colbase, tid, wave, As + nxt * 4096, Bs + nxt * 4096, k0 + 64);
    }

    f16x8 a[4], b[4];
#pragma unroll
    for (int mt = 0; mt < 4; mt++) {
      int r = wrow + mt * 16 + ln;
      a[mt] = *(const f16x8*)(AsC + ((size_t)r * 4 + (quad ^ (r & 3))) * 8);
    }
#pragma unroll
    for (int nt = 0; nt < 4; nt++) {
      int r = wcol + nt * 16 + ln;
      b[nt] = *(const f16x8*)(BsC + ((size_t)r * 4 + (quad ^ (r & 3))) * 8);
    }
    __builtin_amdgcn_s_setprio(1);
#pragma unroll
    for (int mt = 0; mt < 4; mt++)
#pragma unroll
      for (int nt = 0; nt < 4; nt++)
        acc[mt][nt] = __builtin_amdgcn_mfma_f32_16x16x32_f16(a[mt], b[nt], acc[mt][nt], 0, 0, 0);
    __builtin_amdgcn_s_setprio(0);

    cur = cur + 1; if (cur == 3) cur = 0;
  }
}

// ---------------- fused Q + KV projection GEMM ----------------
__global__ __launch_bounds__(256, 3) void qkv_gemm(
    const ushort* __restrict__ xb, const ushort* __restrict__ cb,
    const ushort* __restrict__ WqT, const ushort* __restrict__ WkvT,
    ushort* __restrict__ Qo, ushort* __restrict__ Ko, ushort* __restrict__ Vo) {
  __shared__ ushort As[3 * 128 * 32];
  __shared__ ushort Bs[3 * 128 * 32];
  const int tid = threadIdx.x;
  const int lane = tid & 63, wave = tid >> 6;
  const int quad = lane >> 4, ln = lane & 15;
  const int cy = blockIdx.y;
  const bool isQ = cy < 8;
  const int colbase = (isQ ? cy : cy - 8) * 128;
  const int rowbase = blockIdx.x * 128;
  const int wrow = (wave >> 1) * 64, wcol = (wave & 1) * 64;
  f32x4 acc[4][4] = {};
  gemm_core(isQ ? xb : cb, isQ ? WqT : WkvT, 1024, rowbase, colbase, tid, As, Bs, acc);

  if (isQ) {
    const float qs = 0.18033688011112042f;  // 1/8 * log2(e)
#pragma unroll
    for (int nt = 0; nt < 4; nt++) {
      int col = colbase + wcol + nt * 16 + ln;
      int h = col >> 6, d = col & 63;
#pragma unroll
      for (int mt = 0; mt < 4; mt++) {
        int row = rowbase + wrow + mt * 16 + quad * 4;
        int bb = row >> 11, n = row & 2047;
        uint2 pv;
        pv.x = pkrtz(acc[mt][nt][0] * qs, acc[mt][nt][1] * qs);
        pv.y = pkrtz(acc[mt][nt][2] * qs, acc[mt][nt][3] * qs);
        *(uint2*)(Qo + (((size_t)bb * 16 + h) * 64 + d) * 2048 + n) = pv;
      }
    }
  } else {
    bool isK = (colbase < 1024);
#pragma unroll
    for (int nt = 0; nt < 4; nt++) {
      int col = colbase + wcol + nt * 16 + ln;
#pragma unroll
      for (int mt = 0; mt < 4; mt++) {
        int row = rowbase + wrow + mt * 16 + quad * 4;
        int bb = row >> 11, m = row & 2047;
        if (isK) {
          int h = col >> 6, d = col & 63;
#pragma unroll
          for (int r = 0; r < 4; r++)
            Ko[(((size_t)bb * 16 + h) * 2048 + (m + r)) * 64 + d] = f2h(acc[mt][nt][r]);
        } else {
          int c2 = col - 1024;
          int h = c2 >> 6, d = c2 & 63;
          uint2 pv;
          pv.x = pkrtz(acc[mt][nt][0], acc[mt][nt][1]);
          pv.y = pkrtz(acc[mt][nt][2], acc[mt][nt][3]);
          *(uint2*)(Vo + (((size_t)bb * 16 + h) * 64 + d) * 2048 + m) = pv;
        }
      }
    }
  }
}

// ---------------- out projection: fp32 [M][N] = A @ WoT^T + bias ----------------
__global__ __launch_bounds__(256, 3) void out_gemm(
    const ushort* __restrict__ A, const ushort* __restrict__ Bt,
    float* __restrict__ C, const float* __restrict__ bias) {
  __shared__ ushort As[3 * 128 * 32];
  __shared__ ushort Bs[3 * 128 * 32];
  const int tid = threadIdx.x;
  const int lane = tid & 63, wave = tid >> 6;
  const int quad = lane >> 4, ln = lane & 15;
  const int colbase = blockIdx.y * 128, rowbase = blockIdx.x * 128;
  const int wrow = (wave >> 1) * 64, wcol = (wave & 1) * 64;
  f32x4 acc[4][4] = {};
  gemm_core(A, Bt, 1024, rowbase, colbase, tid, As, Bs, acc);
#pragma unroll
  for (int nt = 0; nt < 4; nt++) {
    int col = colbase + wcol + nt * 16 + ln;
    float bv = bias[col];
#pragma unroll
    for (int mt = 0; mt < 4; mt++) {
      int row = rowbase + wrow + mt * 16 + quad * 4;
#pragma unroll
      for (int r = 0; r < 4; r++)
        C[(size_t)(row + r) * 1024 + col] = acc[mt][nt][r] + bv;
    }
  }
}

// ---------------- flash attention: 4 waves, 64 q/wave, tri-buffer 1-barrier ----------------
// R6 verified structure + EARLY refill: STAGE(kb+2) issued right after the
// barrier (before compute) so its loads land during the ~1500cy compute body
// instead of stalling next iter's vmcnt(4). Safety: buf[(cur+2)%3] holds tile
// kb-1, last read in iter kb-1; all waves released from barrier kb finished
// iter kb-1's reads. vmcnt checkpoints unchanged.
__global__ __launch_bounds__(256, 2) void attn_kernel(
    const ushort* __restrict__ QT, const ushort* __restrict__ K,
    const ushort* __restrict__ VT, const float* __restrict__ xmask,
    const float* __restrict__ cmask, ushort* __restrict__ O) {
  __shared__ ushort Ks[3][64 * 64];  // 24KB tri-buffer
  __shared__ ushort Vs[3][64 * 64];  // 24KB tri-buffer
  __shared__ float CMB[2048];        // (cmask-1)*3e4 bias, whole context row
  const int tid = threadIdx.x, lane = tid & 63, wave = tid >> 6;  // wave 0..3
  const int quad = lane >> 4, ln = lane & 15;
  const int bid = blockIdx.x;
  const int qb = bid >> 6, bh6 = bid & 63, h = bh6 & 15, b = bh6 >> 4;
  const size_t bh = (size_t)b * 16 + h;
  const ushort* QTbh = QT + bh * (64 * 2048);
  const ushort* Kbh = K + bh * (2048 * 64);
  const ushort* Vbh = VT + bh * (64 * 2048);
  const int q0 = qb * 256 + wave * 64;

  // one-time: stage mask bias into LDS (0 valid / -3e4 masked), 8 floats/thread
#pragma unroll
  for (int i = 0; i < 2; i++) {
    float4 c0 = *(const float4*)(cmask + b * 2048 + tid * 8 + i * 4);
    float4 b0;
    b0.x = fmaf(c0.x, 3.0e4f, -3.0e4f); b0.y = fmaf(c0.y, 3.0e4f, -3.0e4f);
    b0.z = fmaf(c0.z, 3.0e4f, -3.0e4f); b0.w = fmaf(c0.w, 3.0e4f, -3.0e4f);
    *(float4*)(CMB + tid * 8 + i * 4) = b0;
  }

  // Q fragments from Q^T (one-time scalar loads; B-operand: n=q=ln, k=d=quad*8+j+32*kc)
  f16x8 qf[4][2];
#pragma unroll
  for (int qt = 0; qt < 4; qt++)
#pragma unroll
    for (int kc = 0; kc < 2; kc++) {
      int q = q0 + qt * 16 + ln;
#pragma unroll
      for (int j = 0; j < 8; j++)
        qf[qt][kc][j] = __builtin_bit_cast(_Float16,
            (unsigned short)QTbh[(size_t)(kc * 32 + quad * 8 + j) * 2048 + q]);
    }

  float xm[4];
#pragma unroll
  for (int qt = 0; qt < 4; qt++) xm[qt] = xmask[b * 2048 + q0 + qt * 16 + ln];

  __syncthreads();  // CMB staged; drains all scalar VMEM (vmcnt clean for pipeline)

  // staging: 2 K-gloads + 2 V-gloads per tile per thread
  auto STAGE = [&](int t, int buf) {
#pragma unroll
    for (int i = 0; i < 2; i++) {
      int f = i * 256 + tid;
      int r = f >> 3;
      int c = (f & 7) ^ (r & 7);
      int rp = (r & 32) | ((r & 12) << 1) | ((r & 16) >> 2) | (r & 3);
      gload_lds16(Kbh + (size_t)(t * 64 + rp) * 64 + c * 8, (char*)Ks[buf] + (size_t)f * 16);
      gload_lds16(Vbh + (size_t)r * 2048 + (t * 64 + c * 8), (char*)Vs[buf] + (size_t)f * 16);
    }
  };

  // prologue: prefetch tiles 0 and 1 into bufs 0 and 1
  STAGE(0, 0);
  STAGE(1, 1);

  // ones A-fragment for the row-sum MFMA (D[r][q] = sum_k P[k][q] for all r)
  f16x8 onesf;
#pragma unroll
  for (int j = 0; j < 8; j++) onesf[j] = (_Float16)1.0f;

  f32x4 o[4][4] = {};    // o[dt][qt]: rows d = dt*16+quad*4+r, col q = ln
  f32x4 lsum[4] = {};    // per-qt row-sum accumulators (all regs equal)

  int cur = 0;
  for (int kb = 0; kb < 32; kb++) {
    const int m0 = kb * 64;
    const ushort* KsC = Ks[cur];
    const ushort* VsC = Vs[cur];

    if (kb < 31) asm volatile("s_waitcnt vmcnt(4)" ::: "memory");
    else         asm volatile("s_waitcnt vmcnt(0)" ::: "memory");
    asm volatile("s_barrier" ::: "memory");

    // EARLY refill: issue tile kb+2's loads now; compute below hides their latency
    if (kb < 30) {
      int nxt = cur - 1; if (nxt < 0) nxt = 2;  // (cur+2)%3
      STAGE(kb + 2, nxt);
    }

    // mask bias from LDS (broadcast reads), at PERMUTED key positions:
    // tile kt rows quad*4+{0..3} hold keys (kt>>1)*32 + quad*8 + (kt&1)*4 + {0..3}
    f32x4 bias4[4];
#pragma unroll
    for (int kt = 0; kt < 4; kt++)
      bias4[kt] = *(const f32x4*)(CMB + m0 + (kt >> 1) * 32 + quad * 8 + (kt & 1) * 4);

    // S^T: s[kt][qt], C-init = mask bias (permuted key order)
    f32x4 s[4][4];
#pragma unroll
    for (int kt = 0; kt < 4; kt++)
#pragma unroll
      for (int qt = 0; qt < 4; qt++) s[kt][qt] = bias4[kt];
    __builtin_amdgcn_s_setprio(1);
#pragma unroll
    for (int kc = 0; kc < 2; kc++) {
#pragma unroll
      for (int kt = 0; kt < 4; kt++) {
        int r = kt * 16 + ln;
        f16x8 ka = *(const f16x8*)(KsC + ((size_t)r * 8 + ((kc * 4 + quad) ^ (r & 7))) * 8);
#pragma unroll
        for (int qt = 0; qt < 4; qt++)
          s[kt][qt] = __builtin_amdgcn_mfma_f32_16x16x32_f16(ka, qf[qt][kc], s[kt][qt], 0, 0, 0);
      }
    }
    __builtin_amdgcn_s_setprio(0);

    // per 32-key half: exp2 -> pack -> PV B-frag entirely in registers;
    // row-sum folded into an extra ones-A MFMA per (kc,qt).
#pragma unroll
    for (int kc = 0; kc < 2; kc++) {
      f16x8 pf[4];
#pragma unroll
      for (int qt = 0; qt < 4; qt++) {
        f32x4 sA = s[kc * 2 + 0][qt];
        f32x4 sB = s[kc * 2 + 1][qt];
        u32x4 u;
        u[0] = pkrtz(EXP2F(sA[0]), EXP2F(sA[1]));
        u[1] = pkrtz(EXP2F(sA[2]), EXP2F(sA[3]));
        u[2] = pkrtz(EXP2F(sB[0]), EXP2F(sB[1]));
        u[3] = pkrtz(EXP2F(sB[2]), EXP2F(sB[3]));
        pf[qt] = __builtin_bit_cast(f16x8, u);
      }
      __builtin_amdgcn_s_setprio(1);
#pragma unroll
      for (int qt = 0; qt < 4; qt++)
        lsum[qt] = __builtin_amdgcn_mfma_f32_16x16x32_f16(onesf, pf[qt], lsum[qt], 0, 0, 0);
#pragma unroll
      for (int dt = 0; dt < 4; dt++) {
        int r = dt * 16 + ln;
        f16x8 va = *(const f16x8*)(VsC + ((size_t)r * 8 + ((kc * 4 + quad) ^ (r & 7))) * 8);
#pragma unroll
        for (int qt = 0; qt < 4; qt++)
          o[dt][qt] = __builtin_amdgcn_mfma_f32_16x16x32_f16(va, pf[qt], o[dt][qt], 0, 0, 0);
      }
      __builtin_amdgcn_s_setprio(0);
    }

    cur = cur + 1; if (cur == 3) cur = 0;
  }

  // normalize + store O [b][n][h*64+d]; l comes straight from lsum (no shfl)
#pragma unroll
  for (int qt = 0; qt < 4; qt++) {
    float l = lsum[qt][0];
    float inv = (xm[qt] != 0.f && l > 0.f) ? (1.f / l) : 0.f;
    int n = q0 + qt * 16 + ln;
    ushort* ob = O + ((size_t)(b * 2048 + n) * 16 + h) * 64;
#pragma unroll
    for (int dt = 0; dt < 4; dt++) {
      uint2 pv;
      pv.x = pkrtz(o[dt][qt][0] * inv, o[dt][qt][1] * inv);
      pv.y = pkrtz(o[dt][qt][2] * inv, o[dt][qt][3] * inv);
      *(uint2*)(ob + dt * 16 + quad * 4) = pv;
    }
  }
}

// ---------------- host launcher ----------------
extern "C" void kernel_launch(void* const* d_in, const int* in_sizes, int n_in,
                              void* d_out, int out_size, void* d_ws, size_t ws_size,
                              hipStream_t stream) {
  const float* x   = (const float*)d_in[0];
  const float* ctx = (const float*)d_in[1];
  const float* xm  = (const float*)d_in[2];
  const float* cm  = (const float*)d_in[3];
  const float* Wq  = (const float*)d_in[4];
  const float* Wkv = (const float*)d_in[5];
  const float* Wo  = (const float*)d_in[6];
  const float* bo  = (const float*)d_in[7];

  char* ws = (char*)d_ws;
  const size_t MB = 1024 * 1024;
  ushort* xb   = (ushort*)(ws + 0);         // 16MB (x fp16; reused as O after QKV GEMM)
  ushort* cb   = (ushort*)(ws + 16 * MB);   // 16MB (context fp16)
  ushort* WqT  = (ushort*)(ws + 32 * MB);   // 2MB
  ushort* WkvT = (ushort*)(ws + 34 * MB);   // 4MB
  ushort* WoT  = (ushort*)(ws + 38 * MB);   // 2MB
  ushort* QTb  = (ushort*)(ws + 40 * MB);   // 16MB (Q transposed [b][h][d][n])
  ushort* Kb   = (ushort*)(ws + 56 * MB);   // 16MB
  ushort* VTb  = (ushort*)(ws + 72 * MB);   // 16MB
  ushort* Ob   = xb;                        // alias: x fp16 dead after QKV GEMM

  prep_kernel<<<17408, 256, 0, stream>>>((const float4*)x, (const float4*)ctx,
                                         (ushort4*)xb, (ushort4*)cb,
                                         Wq, Wkv, Wo, WqT, WkvT, WoT);
  qkv_gemm<<<dim3(64, 24), 256, 0, stream>>>(xb, cb, WqT, WkvT, QTb, Kb, VTb);
  attn_kernel<<<512, 256, 0, stream>>>(QTb, Kb, VTb, xm, cm, Ob);
  out_gemm<<<dim3(64, 8), 256, 0, stream>>>(Ob, WoT, (float*)d_out, bo);
}